// Round 1
// baseline (888.015 us; speedup 1.0000x reference)
//
#include <hip/hip_runtime.h>
#include <hip/hip_bf16.h>

// Problem constants (from reference)
#define B_   64
#define N_   1024
#define S_   64
#define DV   768
#define DT   768
#define HID  256
#define KEEP 96

// ---------------------------------------------------------------------------
// Kernel 1: per-batch text mean-pool + projection through W1[768:1536] + b1.
// ctx_proj[b][h] = b1[h] + sum_d mean_s(text[b][s][d]) * W1[(768+d)*256 + h]
// ---------------------------------------------------------------------------
__global__ __launch_bounds__(256) void ctx_proj_kernel(
    const float* __restrict__ text,   // [B, S, DT]
    const float* __restrict__ W1,     // [DV+DT, HID]
    const float* __restrict__ b1,     // [HID]
    float* __restrict__ ctx_proj) {   // [B, HID]
  int b = blockIdx.x;
  int t = threadIdx.x;
  __shared__ float ctx[DT];
  #pragma unroll
  for (int j = 0; j < DT / 256; ++j) {
    int d = t + j * 256;
    float acc = 0.f;
    const float* p = text + (size_t)b * S_ * DT + d;
    for (int s = 0; s < S_; ++s) acc += p[(size_t)s * DT];
    ctx[d] = acc * (1.0f / S_);
  }
  __syncthreads();
  float acc = b1[t];
  const float* w = W1 + (size_t)DV * HID + t;  // rows 768..1535, col t
  for (int d = 0; d < DT; ++d) acc += ctx[d] * w[(size_t)d * HID];
  ctx_proj[b * HID + t] = acc;
}

// ---------------------------------------------------------------------------
// Kernel 2: fused scorer GEMM (fp32).
// logits[r] = sum_h relu( ctx_proj[b][h] + sum_d A[r][d]*W1[d][h] ) * W2[h]
// Block: 64 rows x 256 hidden, 256 threads, each 8 rows x 8 hidden.
// Thread (tx = t&31, ty = t>>5): rows ty*8..+7, cols {tx*4..+3, 128+tx*4..+3}.
// ---------------------------------------------------------------------------
#define BN 64
#define KB 16

__global__ __launch_bounds__(256, 4) void score_kernel(
    const float* __restrict__ A,         // dense_visual [B*N, DV]
    const float* __restrict__ W1,        // [DV+DT, HID] (we use rows 0..767)
    const float* __restrict__ W2,        // [HID]
    const float* __restrict__ ctx_proj,  // [B, HID]
    float* __restrict__ logits) {        // [B*N]
  __shared__ float As[KB][68];      // padded: stage-write 2-way max (free)
  __shared__ float Ws[KB][HID];
  __shared__ float red[BN][33];

  int t  = threadIdx.x;
  int tx = t & 31, ty = t >> 5;
  int r0 = blockIdx.x * BN;
  int batch = r0 >> 10;             // 1024 rows per batch

  // staging assignments
  int arow = t >> 2, akq = (t & 3) << 2;       // A: 64 rows x 16 k
  const float* Aptr = A + (size_t)(r0 + arow) * DV + akq;
  int kw = t >> 4, cw = (t & 15) << 4;         // W: 16 k-rows x 256 cols
  const float* Wptr = W1 + (size_t)kw * HID + cw;

  // prologue loads (k-tile 0)
  float4 av  = *(const float4*)Aptr;
  float4 wv0 = *(const float4*)(Wptr + 0);
  float4 wv1 = *(const float4*)(Wptr + 4);
  float4 wv2 = *(const float4*)(Wptr + 8);
  float4 wv3 = *(const float4*)(Wptr + 12);

  float acc[8][8];
  {
    const float* cp = ctx_proj + batch * HID;
    float4 c0 = *(const float4*)(cp + tx * 4);
    float4 c1 = *(const float4*)(cp + 128 + tx * 4);
    #pragma unroll
    for (int i = 0; i < 8; ++i) {
      acc[i][0] = c0.x; acc[i][1] = c0.y; acc[i][2] = c0.z; acc[i][3] = c0.w;
      acc[i][4] = c1.x; acc[i][5] = c1.y; acc[i][6] = c1.z; acc[i][7] = c1.w;
    }
  }

  const int NKT = DV / KB;  // 48
  for (int kt = 0; kt < NKT; ++kt) {
    __syncthreads();  // previous tile's compute done
    As[akq + 0][arow] = av.x;
    As[akq + 1][arow] = av.y;
    As[akq + 2][arow] = av.z;
    As[akq + 3][arow] = av.w;
    *(float4*)&Ws[kw][cw + 0]  = wv0;
    *(float4*)&Ws[kw][cw + 4]  = wv1;
    *(float4*)&Ws[kw][cw + 8]  = wv2;
    *(float4*)&Ws[kw][cw + 12] = wv3;
    __syncthreads();
    if (kt + 1 < NKT) {  // prefetch next k-tile; latency hidden by compute below
      const float* ap = Aptr + (kt + 1) * KB;
      const float* wp = Wptr + (size_t)(kt + 1) * KB * HID;
      av  = *(const float4*)ap;
      wv0 = *(const float4*)(wp + 0);
      wv1 = *(const float4*)(wp + 4);
      wv2 = *(const float4*)(wp + 8);
      wv3 = *(const float4*)(wp + 12);
    }
    #pragma unroll
    for (int k = 0; k < KB; ++k) {
      float4 a0 = *(const float4*)&As[k][ty * 8];      // wave-broadcast
      float4 a1 = *(const float4*)&As[k][ty * 8 + 4];
      float4 w0 = *(const float4*)&Ws[k][tx * 4];      // sequential 16B/lane
      float4 w1 = *(const float4*)&Ws[k][128 + tx * 4];
      float a[8] = {a0.x, a0.y, a0.z, a0.w, a1.x, a1.y, a1.z, a1.w};
      float w[8] = {w0.x, w0.y, w0.z, w0.w, w1.x, w1.y, w1.z, w1.w};
      #pragma unroll
      for (int i = 0; i < 8; ++i)
        #pragma unroll
        for (int j = 0; j < 8; ++j)
          acc[i][j] = fmaf(a[i], w[j], acc[i][j]);
    }
  }

  // epilogue: relu + dot with W2, reduce 32 column-groups per row
  float w2[8];
  {
    float4 u0 = *(const float4*)(W2 + tx * 4);
    float4 u1 = *(const float4*)(W2 + 128 + tx * 4);
    w2[0] = u0.x; w2[1] = u0.y; w2[2] = u0.z; w2[3] = u0.w;
    w2[4] = u1.x; w2[5] = u1.y; w2[6] = u1.z; w2[7] = u1.w;
  }
  #pragma unroll
  for (int i = 0; i < 8; ++i) {
    float p = 0.f;
    #pragma unroll
    for (int j = 0; j < 8; ++j) p = fmaf(fmaxf(acc[i][j], 0.f), w2[j], p);
    red[ty * 8 + i][tx] = p;
  }
  __syncthreads();
  if (t < BN) {
    float sum = 0.f;
    #pragma unroll
    for (int j = 0; j < 32; ++j) sum += red[t][j];  // pad-33 → 2-way max (free)
    logits[r0 + t] = sum;
  }
}

// ---------------------------------------------------------------------------
// Kernel 3: per-batch top-96 (JAX tie-break: lower index first), then sort
// the 96 indices ascending. Bitonic sorts in LDS.
// ---------------------------------------------------------------------------
__global__ __launch_bounds__(1024) void topk_kernel(
    const float* __restrict__ logits,  // [B, N]
    int* __restrict__ idx_ws,          // [B, KEEP]
    float* __restrict__ out,           // d_out; idx tail at out_idx_base
    int out_idx_base) {
  int b = blockIdx.x;
  int t = threadIdx.x;
  __shared__ float s[N_];
  __shared__ int   si[N_];
  __shared__ int   t2[128];

  s[t]  = logits[b * N_ + t];
  si[t] = t;
  __syncthreads();

  // bitonic sort: final order = descending score, ties -> lower index first
  for (int k = 2; k <= N_; k <<= 1) {
    for (int j = k >> 1; j > 0; j >>= 1) {
      int ixj = t ^ j;
      if (ixj > t) {
        float s1 = s[t], s2 = s[ixj];
        int   i1 = si[t], i2 = si[ixj];
        bool before = (s1 > s2) || (s1 == s2 && i1 < i2);
        bool doSwap = ((t & k) == 0) ? !before : before;
        if (doSwap) { s[t] = s2; s[ixj] = s1; si[t] = i2; si[ixj] = i1; }
      }
      __syncthreads();
    }
  }

  if (t < 128) t2[t] = (t < KEEP) ? si[t] : 0x7FFFFFFF;
  __syncthreads();
  // sort 96 indices ascending (padded to 128)
  for (int k = 2; k <= 128; k <<= 1) {
    for (int j = k >> 1; j > 0; j >>= 1) {
      if (t < 128) {
        int ixj = t ^ j;
        if (ixj > t) {
          int a = t2[t], c = t2[ixj];
          bool before = a < c;
          bool doSwap = ((t & k) == 0) ? !before : before;
          if (doSwap) { t2[t] = c; t2[ixj] = a; }
        }
      }
      __syncthreads();
    }
  }

  if (t < KEEP) {
    int v = t2[t];
    idx_ws[b * KEEP + t] = v;
    out[out_idx_base + b * KEEP + t] = (float)v;  // int32 output cast to float
  }
}

// ---------------------------------------------------------------------------
// Kernel 4: gather selected rows + append register token.
// One block per output row (B*97), 192 threads x float4 = 768 floats.
// ---------------------------------------------------------------------------
__global__ __launch_bounds__(192) void gather_kernel(
    const float* __restrict__ A,        // dense_visual [B, N, DV]
    const float* __restrict__ reg_tok,  // [DV]
    const int* __restrict__ idx_ws,     // [B, KEEP]
    float* __restrict__ out) {          // [B, KEEP+1, DV]
  int blk = blockIdx.x;
  int b = blk / (KEEP + 1), r = blk % (KEEP + 1);
  int t = threadIdx.x;
  const float* src;
  if (r == KEEP) {
    src = reg_tok;
  } else {
    int idx = idx_ws[b * KEEP + r];
    src = A + ((size_t)b * N_ + idx) * DV;
  }
  float4 v = *(const float4*)&src[t * 4];
  *(float4*)&out[((size_t)b * (KEEP + 1) + r) * DV + t * 4] = v;
}

// ---------------------------------------------------------------------------
extern "C" void kernel_launch(void* const* d_in, const int* in_sizes, int n_in,
                              void* d_out, int out_size, void* d_ws, size_t ws_size,
                              hipStream_t stream) {
  (void)in_sizes; (void)n_in; (void)out_size; (void)ws_size;
  const float* dense_visual = (const float*)d_in[0];  // [B,N,DV]
  const float* text_emb     = (const float*)d_in[1];  // [B,S,DT]
  const float* W1           = (const float*)d_in[2];  // [1536,256]
  const float* b1           = (const float*)d_in[3];  // [256]
  const float* W2           = (const float*)d_in[4];  // [256]
  // d_in[5] = b2 : monotonic shift, irrelevant to top-k -> unused
  const float* reg_tok      = (const float*)d_in[6];  // [768]
  float* out = (float*)d_out;

  // workspace layout (floats): ctx_proj [B*HID] | logits [B*N] | idx [B*KEEP]
  float* ws       = (float*)d_ws;
  float* ctx_proj = ws;                       // 16384 floats
  float* logits   = ws + B_ * HID;            // 65536 floats
  int*   idx_ws   = (int*)(ws + B_ * HID + B_ * N_);

  const int out_idx_base = B_ * (KEEP + 1) * DV;  // final_visual elements

  ctx_proj_kernel<<<B_, 256, 0, stream>>>(text_emb, W1, b1, ctx_proj);
  score_kernel<<<(B_ * N_) / BN, 256, 0, stream>>>(dense_visual, W1, W2, ctx_proj, logits);
  topk_kernel<<<B_, 1024, 0, stream>>>(logits, idx_ws, out, out_idx_base);
  gather_kernel<<<B_ * (KEEP + 1), 192, 0, stream>>>(dense_visual, reg_tok, idx_ws, out);
}

// Round 2
// 389.429 us; speedup vs baseline: 2.2803x; 2.2803x over previous
//
#include <hip/hip_runtime.h>
#include <hip/hip_bf16.h>

// Problem constants (from reference)
#define B_   64
#define N_   1024
#define S_   64
#define DV   768
#define DT   768
#define HID  256
#define KEEP 96

#define NKS (DV / 32)      // 24 K-steps of 32
#define SCALE_A 32.0f      // ranking-invariant scaling (relu pos-homogeneous)
#define SCALE_W 32.0f
#define SCALE_LOGIT (SCALE_A * SCALE_W)

typedef _Float16 half8_t __attribute__((ext_vector_type(8)));  // 4 VGPRs
typedef float f32x4 __attribute__((ext_vector_type(4)));

// ---------------------------------------------------------------------------
// Kernel 0: split W1[0:768][:] (scaled x32) into f16 hi/lo, stored in MFMA
// B-fragment lane order: Wpack[ks][c][lane][i] holds
// W[ks*32 + (lane>>4)*8 + i][c*16 + (lane&15)].
// ---------------------------------------------------------------------------
__global__ __launch_bounds__(256) void pack_w_kernel(
    const float* __restrict__ W1, _Float16* __restrict__ Wh,
    _Float16* __restrict__ Wl) {
  int d = blockIdx.x;    // 0..767
  int h = threadIdx.x;   // 0..255
  float w = W1[d * HID + h] * SCALE_W;
  _Float16 hi = (_Float16)w;
  _Float16 lo = (_Float16)(w - (float)hi);
  int ks = d >> 5, r = d & 31;
  int lane = ((r >> 3) << 4) | (h & 15);
  int i = r & 7, c = h >> 4;
  size_t off = ((size_t)((ks * 16 + c) * 64 + lane)) * 8 + i;
  Wh[off] = hi;
  Wl[off] = lo;
}

// ---------------------------------------------------------------------------
// Kernel 1: ctx_proj[b][h] = 1024*(b1[h] + mean_s(text) . W1[768:1536][h])
// (exact fp32; scaled to match the scaled MFMA accumulator)
// ---------------------------------------------------------------------------
__global__ __launch_bounds__(256) void ctx_proj_kernel(
    const float* __restrict__ text,   // [B, S, DT]
    const float* __restrict__ W1,     // [DV+DT, HID]
    const float* __restrict__ b1,     // [HID]
    float* __restrict__ ctx_proj) {   // [B, HID]
  int b = blockIdx.x;
  int t = threadIdx.x;
  __shared__ float ctx[DT];
  #pragma unroll
  for (int j = 0; j < DT / 256; ++j) {
    int d = t + j * 256;
    float acc = 0.f;
    const float* p = text + (size_t)b * S_ * DT + d;
    for (int s = 0; s < S_; ++s) acc += p[(size_t)s * DT];
    ctx[d] = acc * (1.0f / S_);
  }
  __syncthreads();
  const float* wcol = W1 + (size_t)DV * HID + t;
  float s0 = 0.f, s1 = 0.f, s2 = 0.f, s3 = 0.f;
  for (int d = 0; d < DT; d += 4) {
    s0 = fmaf(ctx[d + 0], wcol[(size_t)(d + 0) * HID], s0);
    s1 = fmaf(ctx[d + 1], wcol[(size_t)(d + 1) * HID], s1);
    s2 = fmaf(ctx[d + 2], wcol[(size_t)(d + 2) * HID], s2);
    s3 = fmaf(ctx[d + 3], wcol[(size_t)(d + 3) * HID], s3);
  }
  ctx_proj[b * HID + t] = SCALE_LOGIT * (b1[t] + ((s0 + s1) + (s2 + s3)));
}

// ---------------------------------------------------------------------------
// Kernel 2: MFMA f16x3 scorer.
// logits[r] = sum_h relu( ctxp[b][h] + 1024 * sum_d A[r][d]*W1[d][h] ) * W2[h]
// Block: 64 rows x 256 hidden, 4 waves; wave w owns cols [w*64, w*64+64).
// mfma_f32_16x16x32_f16: A lane l: row=l&15, k=(l>>4)*8+i;
//                        B lane l: col=l&15, k=(l>>4)*8+i;
//                        C lane l: col=l&15, row=(l>>4)*4+r (m89-verified).
// ---------------------------------------------------------------------------
__global__ __launch_bounds__(256, 2) void score_kernel(
    const float* __restrict__ A,          // dense_visual [B*N, DV]
    const _Float16* __restrict__ WhP,     // packed hi [24][16][64][8]
    const _Float16* __restrict__ WlP,     // packed lo
    const float* __restrict__ W2,         // [HID]
    const float* __restrict__ ctx_proj,   // [B, HID] (scaled)
    float* __restrict__ logits) {         // [B*N] (scaled)
  __shared__ half8_t AhS[4 * 64];   // [row-tile][lane] fragment order (4 KB)
  __shared__ half8_t AlS[4 * 64];
  __shared__ float red[64][4];

  const int t = threadIdx.x;
  const int lane = t & 63;
  const int w = t >> 6;
  const int r0 = blockIdx.x * 64;
  const int batch = r0 >> 10;

  // A staging: thread t loads row arow, 8 consecutive k at akq
  const int arow = t >> 2;
  const int akq = (t & 3) * 8;
  const float* aptr = A + (size_t)(r0 + arow) * DV + akq;
  const int adst = ((arow >> 4) * 64) + ((t & 3) << 4) + (arow & 15);

  const half8_t* WhV = (const half8_t*)WhP;
  const half8_t* WlV = (const half8_t*)WlP;

  f32x4 acc[4][4];
  #pragma unroll
  for (int rt = 0; rt < 4; ++rt)
    #pragma unroll
    for (int j = 0; j < 4; ++j) acc[rt][j] = (f32x4){0.f, 0.f, 0.f, 0.f};

  // prologue: k-step 0 prefetch
  float4 a0 = *(const float4*)aptr;
  float4 a1 = *(const float4*)(aptr + 4);
  half8_t bh[2][4], bl[2][4];
  #pragma unroll
  for (int j = 0; j < 4; ++j) {
    int bi = (w * 4 + j) * 64 + lane;
    bh[0][j] = WhV[bi];
    bl[0][j] = WlV[bi];
  }

  #pragma unroll 2
  for (int ks = 0; ks < NKS; ++ks) {
    const int cur = ks & 1, nxt = cur ^ 1;
    // convert this thread's 8 A values to scaled f16 hi/lo
    half8_t hi8, lo8;
    {
      float av[8] = {a0.x, a0.y, a0.z, a0.w, a1.x, a1.y, a1.z, a1.w};
      #pragma unroll
      for (int i = 0; i < 8; ++i) {
        float x = av[i] * SCALE_A;
        _Float16 h = (_Float16)x;
        hi8[i] = h;
        lo8[i] = (_Float16)(x - (float)h);
      }
    }
    __syncthreads();          // prior tile's frag reads complete
    AhS[adst] = hi8;          // ds_write_b128, conflict-free
    AlS[adst] = lo8;
    __syncthreads();
    if (ks + 1 < NKS) {       // prefetch next tile (overlaps MFMA below)
      const float* ap = aptr + (ks + 1) * 32;
      a0 = *(const float4*)ap;
      a1 = *(const float4*)(ap + 4);
      #pragma unroll
      for (int j = 0; j < 4; ++j) {
        int bi = ((ks + 1) * 16 + w * 4 + j) * 64 + lane;
        bh[nxt][j] = WhV[bi];
        bl[nxt][j] = WlV[bi];
      }
    }
    half8_t ah[4], al[4];
    #pragma unroll
    for (int rt = 0; rt < 4; ++rt) {
      ah[rt] = AhS[rt * 64 + lane];   // ds_read_b128, conflict-free
      al[rt] = AlS[rt * 64 + lane];
    }
    #pragma unroll
    for (int rt = 0; rt < 4; ++rt)
      #pragma unroll
      for (int j = 0; j < 4; ++j) {
        acc[rt][j] = __builtin_amdgcn_mfma_f32_16x16x32_f16(ah[rt], bh[cur][j], acc[rt][j], 0, 0, 0);
        acc[rt][j] = __builtin_amdgcn_mfma_f32_16x16x32_f16(ah[rt], bl[cur][j], acc[rt][j], 0, 0, 0);
        acc[rt][j] = __builtin_amdgcn_mfma_f32_16x16x32_f16(al[rt], bh[cur][j], acc[rt][j], 0, 0, 0);
      }
  }

  // epilogue: +ctx, relu, dot W2 over this wave's 64 cols, reduce
  const int hbase = w * 64 + (lane & 15);
  const float* ctxp = ctx_proj + batch * HID;
  float psum[4][4];
  #pragma unroll
  for (int rt = 0; rt < 4; ++rt)
    #pragma unroll
    for (int r = 0; r < 4; ++r) psum[rt][r] = 0.f;
  #pragma unroll
  for (int j = 0; j < 4; ++j) {
    int hcol = hbase + j * 16;
    float cj = ctxp[hcol];
    float w2j = W2[hcol];
    #pragma unroll
    for (int rt = 0; rt < 4; ++rt)
      #pragma unroll
      for (int r = 0; r < 4; ++r)
        psum[rt][r] = fmaf(fmaxf(acc[rt][j][r] + cj, 0.f), w2j, psum[rt][r]);
  }
  #pragma unroll
  for (int m = 1; m < 16; m <<= 1)
    #pragma unroll
    for (int rt = 0; rt < 4; ++rt)
      #pragma unroll
      for (int r = 0; r < 4; ++r)
        psum[rt][r] += __shfl_xor(psum[rt][r], m, 64);
  if ((lane & 15) == 0) {
    int rowg = (lane >> 4) * 4;
    #pragma unroll
    for (int rt = 0; rt < 4; ++rt)
      #pragma unroll
      for (int r = 0; r < 4; ++r) red[rt * 16 + rowg + r][w] = psum[rt][r];
  }
  __syncthreads();
  if (t < 64) logits[r0 + t] = red[t][0] + red[t][1] + red[t][2] + red[t][3];
}

// ---------------------------------------------------------------------------
// Kernel 3: per-batch top-96 (ties -> lower index), then sort indices asc.
// ---------------------------------------------------------------------------
__global__ __launch_bounds__(1024) void topk_kernel(
    const float* __restrict__ logits,  // [B, N]
    int* __restrict__ idx_ws,          // [B, KEEP]
    float* __restrict__ out,           // d_out; idx tail at out_idx_base
    int out_idx_base) {
  int b = blockIdx.x;
  int t = threadIdx.x;
  __shared__ float s[N_];
  __shared__ int   si[N_];
  __shared__ int   t2[128];

  s[t]  = logits[b * N_ + t];
  si[t] = t;
  __syncthreads();

  for (int k = 2; k <= N_; k <<= 1) {
    for (int j = k >> 1; j > 0; j >>= 1) {
      int ixj = t ^ j;
      if (ixj > t) {
        float s1 = s[t], s2 = s[ixj];
        int   i1 = si[t], i2 = si[ixj];
        bool before = (s1 > s2) || (s1 == s2 && i1 < i2);
        bool doSwap = ((t & k) == 0) ? !before : before;
        if (doSwap) { s[t] = s2; s[ixj] = s1; si[t] = i2; si[ixj] = i1; }
      }
      __syncthreads();
    }
  }

  if (t < 128) t2[t] = (t < KEEP) ? si[t] : 0x7FFFFFFF;
  __syncthreads();
  for (int k = 2; k <= 128; k <<= 1) {
    for (int j = k >> 1; j > 0; j >>= 1) {
      if (t < 128) {
        int ixj = t ^ j;
        if (ixj > t) {
          int a = t2[t], c = t2[ixj];
          bool before = a < c;
          bool doSwap = ((t & k) == 0) ? !before : before;
          if (doSwap) { t2[t] = c; t2[ixj] = a; }
        }
      }
      __syncthreads();
    }
  }

  if (t < KEEP) {
    int v = t2[t];
    idx_ws[b * KEEP + t] = v;
    out[out_idx_base + b * KEEP + t] = (float)v;
  }
}

// ---------------------------------------------------------------------------
// Kernel 4: gather selected rows + register token.
// ---------------------------------------------------------------------------
__global__ __launch_bounds__(192) void gather_kernel(
    const float* __restrict__ A,        // dense_visual [B, N, DV]
    const float* __restrict__ reg_tok,  // [DV]
    const int* __restrict__ idx_ws,     // [B, KEEP]
    float* __restrict__ out) {          // [B, KEEP+1, DV]
  int blk = blockIdx.x;
  int b = blk / (KEEP + 1), r = blk % (KEEP + 1);
  int t = threadIdx.x;
  const float* src;
  if (r == KEEP) {
    src = reg_tok;
  } else {
    int idx = idx_ws[b * KEEP + r];
    src = A + ((size_t)b * N_ + idx) * DV;
  }
  float4 v = *(const float4*)&src[t * 4];
  *(float4*)&out[((size_t)b * (KEEP + 1) + r) * DV + t * 4] = v;
}

// ---------------------------------------------------------------------------
extern "C" void kernel_launch(void* const* d_in, const int* in_sizes, int n_in,
                              void* d_out, int out_size, void* d_ws, size_t ws_size,
                              hipStream_t stream) {
  (void)in_sizes; (void)n_in; (void)out_size; (void)ws_size;
  const float* dense_visual = (const float*)d_in[0];
  const float* text_emb     = (const float*)d_in[1];
  const float* W1           = (const float*)d_in[2];
  const float* b1           = (const float*)d_in[3];
  const float* W2           = (const float*)d_in[4];
  // d_in[5] = b2: monotonic shift, irrelevant to ranking
  const float* reg_tok      = (const float*)d_in[6];
  float* out = (float*)d_out;

  // ws layout (bytes):
  //   ctx_proj: 64*256*4      =  65536   @ 0
  //   logits  : 64*1024*4     = 262144   @ 65536
  //   idx     : 64*96*4       =  24576   @ 327680
  //   Wh      : 768*256*2     = 393216   @ 352256 (16B aligned)
  //   Wl      : 768*256*2     = 393216   @ 745472
  char* ws = (char*)d_ws;
  float*     ctx_proj = (float*)(ws + 0);
  float*     logits   = (float*)(ws + 65536);
  int*       idx_ws   = (int*)(ws + 327680);
  _Float16*  Wh       = (_Float16*)(ws + 352256);
  _Float16*  Wl       = (_Float16*)(ws + 745472);

  const int out_idx_base = B_ * (KEEP + 1) * DV;

  pack_w_kernel<<<DV, 256, 0, stream>>>(W1, Wh, Wl);
  ctx_proj_kernel<<<B_, 256, 0, stream>>>(text_emb, W1, b1, ctx_proj);
  score_kernel<<<(B_ * N_) / 64, 256, 0, stream>>>(dense_visual, Wh, Wl, W2, ctx_proj, logits);
  topk_kernel<<<B_, 1024, 0, stream>>>(logits, idx_ws, out, out_idx_base);
  gather_kernel<<<B_ * (KEEP + 1), 192, 0, stream>>>(dense_visual, reg_tok, idx_ws, out);
}

// Round 4
// 378.695 us; speedup vs baseline: 2.3449x; 1.0283x over previous
//
#include <hip/hip_runtime.h>
#include <hip/hip_bf16.h>

// Problem constants (from reference)
#define B_   64
#define N_   1024
#define S_   64
#define DV   768
#define DT   768
#define HID  256
#define KEEP 96

#define KB2  64            // K per staged tile
#define NKS2 (DV / KB2)    // 12 K-steps
#define SCALE_A 32.0f      // ranking-invariant scaling (relu pos-homogeneous)
#define SCALE_W 32.0f
#define SCALE_LOGIT (SCALE_A * SCALE_W)

typedef _Float16 half8_t __attribute__((ext_vector_type(8)));  // 4 VGPRs
typedef float f32x4 __attribute__((ext_vector_type(4)));

// ---------------------------------------------------------------------------
// Kernel 0: split W1[0:768][:] (scaled x32) into f16 hi/lo, stored in MFMA
// B-fragment lane order: for 32-k-group g=d>>5: Wpack[(g*16 + c)*64 + lane][i]
// holds W[g*32 + (lane>>4)*8 + i][c*16 + (lane&15)].
// ---------------------------------------------------------------------------
__global__ __launch_bounds__(256) void pack_w_kernel(
    const float* __restrict__ W1, _Float16* __restrict__ Wh,
    _Float16* __restrict__ Wl) {
  int d = blockIdx.x;    // 0..767
  int h = threadIdx.x;   // 0..255
  float w = W1[d * HID + h] * SCALE_W;
  _Float16 hi = (_Float16)w;
  _Float16 lo = (_Float16)(w - (float)hi);
  int g = d >> 5, r = d & 31;
  int lane = ((r >> 3) << 4) | (h & 15);
  int i = r & 7, c = h >> 4;
  size_t off = ((size_t)((g * 16 + c) * 64 + lane)) * 8 + i;
  Wh[off] = hi;
  Wl[off] = lo;
}

// ---------------------------------------------------------------------------
// Kernel 1: ctx_proj[b][h] = 1024*(b1[h] + mean_s(text) . W1[768:1536][h])
// 1024 threads: phase1 mean (768 threads, 1 d each); phase2 4-way K-split.
// ---------------------------------------------------------------------------
__global__ __launch_bounds__(1024) void ctx_proj_kernel(
    const float* __restrict__ text,   // [B, S, DT]
    const float* __restrict__ W1,     // [DV+DT, HID]
    const float* __restrict__ b1,     // [HID]
    float* __restrict__ ctx_proj) {   // [B, HID]
  int b = blockIdx.x;
  int t = threadIdx.x;
  __shared__ float ctx[DT];
  __shared__ float red[4][HID];
  if (t < DT) {
    const float* p = text + (size_t)b * S_ * DT + t;
    float a0 = 0.f, a1 = 0.f, a2 = 0.f, a3 = 0.f;
    for (int s = 0; s < S_; s += 4) {
      a0 += p[(size_t)(s + 0) * DT];
      a1 += p[(size_t)(s + 1) * DT];
      a2 += p[(size_t)(s + 2) * DT];
      a3 += p[(size_t)(s + 3) * DT];
    }
    ctx[t] = ((a0 + a1) + (a2 + a3)) * (1.0f / S_);
  }
  __syncthreads();
  int p4 = t >> 8;        // 0..3
  int h  = t & 255;
  int db = p4 * 192;
  const float* wcol = W1 + (size_t)(DV + db) * HID + h;
  float s0 = 0.f, s1 = 0.f, s2 = 0.f, s3 = 0.f;
  #pragma unroll 4
  for (int d = 0; d < 192; d += 4) {
    s0 = fmaf(ctx[db + d + 0], wcol[(size_t)(d + 0) * HID], s0);
    s1 = fmaf(ctx[db + d + 1], wcol[(size_t)(d + 1) * HID], s1);
    s2 = fmaf(ctx[db + d + 2], wcol[(size_t)(d + 2) * HID], s2);
    s3 = fmaf(ctx[db + d + 3], wcol[(size_t)(d + 3) * HID], s3);
  }
  red[p4][h] = ((s0 + s1) + (s2 + s3));
  __syncthreads();
  if (t < HID)
    ctx_proj[b * HID + t] =
        SCALE_LOGIT * (b1[t] + ((red[0][t] + red[1][t]) + (red[2][t] + red[3][t])));
}

// ---------------------------------------------------------------------------
// Kernel 2: MFMA f16x3 scorer, K-step 64, double-buffered A LDS, 1 barrier
// per K-step. Block: 64 rows x 256 hidden, 4 waves; wave w -> cols [w*64,+64).
// ---------------------------------------------------------------------------
__device__ inline void cvt_split8(float4 a, float4 b, half8_t& hi, half8_t& lo) {
  float x[8] = {a.x, a.y, a.z, a.w, b.x, b.y, b.z, b.w};
  #pragma unroll
  for (int i = 0; i < 8; ++i) {
    float v = x[i] * SCALE_A;
    _Float16 h = (_Float16)v;
    hi[i] = h;
    lo[i] = (_Float16)(v - (float)h);
  }
}

__global__ __launch_bounds__(256, 2) void score_kernel(
    const float* __restrict__ A,          // dense_visual [B*N, DV]
    const _Float16* __restrict__ WhP,     // packed hi [(24*16)*64][8]
    const _Float16* __restrict__ WlP,     // packed lo
    const float* __restrict__ W2,         // [HID]
    const float* __restrict__ ctx_proj,   // [B, HID] (scaled)
    float* __restrict__ logits) {         // [B*N] (scaled)
  // A-tile layout (half8 units): [(ksub*4 + kq)*64 + row], ksub<2, kq<4, row<64
  __shared__ half8_t AhS[2][512];   // 16 KB
  __shared__ half8_t AlS[2][512];   // 16 KB
  __shared__ float red[64][4];

  const int t = threadIdx.x;
  const int lane = t & 63;
  const int w = t >> 6;
  const int r0 = blockIdx.x * 64;
  const int batch = r0 >> 10;

  // staging: thread t loads row (t>>2), 16 consecutive k at (t&3)*16
  const int arow = t >> 2;
  const int k0 = (t & 3) * 16;
  const float* aptr = A + (size_t)(r0 + arow) * DV + k0;
  const int ksub0 = k0 >> 5;
  const int kq0 = (k0 & 31) >> 3;          // 0 or 2
  const int dst1 = (ksub0 * 4 + kq0) * 64 + arow;
  const int dst2 = dst1 + 64;

  const half8_t* WhV = (const half8_t*)WhP;
  const half8_t* WlV = (const half8_t*)WlP;

  f32x4 acc[4][4];
  #pragma unroll
  for (int rt = 0; rt < 4; ++rt)
    #pragma unroll
    for (int j = 0; j < 4; ++j) acc[rt][j] = (f32x4){0.f, 0.f, 0.f, 0.f};

  // prologue: stage K-step 0 into buffer 0
  {
    float4 v0 = *(const float4*)(aptr + 0);
    float4 v1 = *(const float4*)(aptr + 4);
    float4 v2 = *(const float4*)(aptr + 8);
    float4 v3 = *(const float4*)(aptr + 12);
    half8_t h0, l0, h1, l1;
    cvt_split8(v0, v1, h0, l0);
    cvt_split8(v2, v3, h1, l1);
    AhS[0][dst1] = h0; AlS[0][dst1] = l0;
    AhS[0][dst2] = h1; AlS[0][dst2] = l1;
  }
  __syncthreads();

  #pragma unroll 2
  for (int ks = 0; ks < NKS2; ++ks) {
    const int cur = ks & 1;
    // issue next A-tile global loads first (latency hides under MFMA below)
    float4 nv0, nv1, nv2, nv3;
    if (ks + 1 < NKS2) {
      const float* ap = aptr + (ks + 1) * KB2;
      nv0 = *(const float4*)(ap + 0);
      nv1 = *(const float4*)(ap + 4);
      nv2 = *(const float4*)(ap + 8);
      nv3 = *(const float4*)(ap + 12);
    }
    #pragma unroll
    for (int ksub = 0; ksub < 2; ++ksub) {
      // B fragments for this 32-k group (L2-resident)
      half8_t bh[4], bl[4];
      #pragma unroll
      for (int j = 0; j < 4; ++j) {
        int bi = ((ks * 2 + ksub) * 16 + w * 4 + j) * 64 + lane;
        bh[j] = WhV[bi];
        bl[j] = WlV[bi];
      }
      half8_t ah[4], al[4];
      #pragma unroll
      for (int rt = 0; rt < 4; ++rt) {
        int ai = (ksub * 4 + (lane >> 4)) * 64 + rt * 16 + (lane & 15);
        ah[rt] = AhS[cur][ai];
        al[rt] = AlS[cur][ai];
      }
      #pragma unroll
      for (int rt = 0; rt < 4; ++rt)
        #pragma unroll
        for (int j = 0; j < 4; ++j) {
          acc[rt][j] = __builtin_amdgcn_mfma_f32_16x16x32_f16(ah[rt], bh[j], acc[rt][j], 0, 0, 0);
          acc[rt][j] = __builtin_amdgcn_mfma_f32_16x16x32_f16(ah[rt], bl[j], acc[rt][j], 0, 0, 0);
          acc[rt][j] = __builtin_amdgcn_mfma_f32_16x16x32_f16(al[rt], bh[j], acc[rt][j], 0, 0, 0);
        }
    }
    if (ks + 1 < NKS2) {   // convert (VALU overlaps MFMA) + stage to other buf
      half8_t h0, l0, h1, l1;
      cvt_split8(nv0, nv1, h0, l0);
      cvt_split8(nv2, nv3, h1, l1);
      AhS[cur ^ 1][dst1] = h0; AlS[cur ^ 1][dst1] = l0;
      AhS[cur ^ 1][dst2] = h1; AlS[cur ^ 1][dst2] = l1;
    }
    __syncthreads();
  }

  // epilogue: +ctx, relu, dot W2 over this wave's 64 cols, reduce
  const int hbase = w * 64 + (lane & 15);
  const float* ctxp = ctx_proj + batch * HID;
  float psum[4][4];
  #pragma unroll
  for (int rt = 0; rt < 4; ++rt)
    #pragma unroll
    for (int r = 0; r < 4; ++r) psum[rt][r] = 0.f;
  #pragma unroll
  for (int j = 0; j < 4; ++j) {
    int hcol = hbase + j * 16;
    float cj = ctxp[hcol];
    float w2j = W2[hcol];
    #pragma unroll
    for (int rt = 0; rt < 4; ++rt)
      #pragma unroll
      for (int r = 0; r < 4; ++r)
        psum[rt][r] = fmaf(fmaxf(acc[rt][j][r] + cj, 0.f), w2j, psum[rt][r]);
  }
  #pragma unroll
  for (int m = 1; m < 16; m <<= 1)
    #pragma unroll
    for (int rt = 0; rt < 4; ++rt)
      #pragma unroll
      for (int r = 0; r < 4; ++r)
        psum[rt][r] += __shfl_xor(psum[rt][r], m, 64);
  if ((lane & 15) == 0) {
    int rowg = (lane >> 4) * 4;
    #pragma unroll
    for (int rt = 0; rt < 4; ++rt)
      #pragma unroll
      for (int r = 0; r < 4; ++r) red[rt * 16 + rowg + r][w] = psum[rt][r];
  }
  __syncthreads();
  if (t < 64) logits[r0 + t] = red[t][0] + red[t][1] + red[t][2] + red[t][3];
}

// ---------------------------------------------------------------------------
// Kernel 3: per-batch top-96 (ties -> lower index), then sort indices asc.
// ---------------------------------------------------------------------------
__global__ __launch_bounds__(1024) void topk_kernel(
    const float* __restrict__ logits,  // [B, N]
    int* __restrict__ idx_ws,          // [B, KEEP]
    float* __restrict__ out,           // d_out; idx tail at out_idx_base
    int out_idx_base) {
  int b = blockIdx.x;
  int t = threadIdx.x;
  __shared__ float s[N_];
  __shared__ int   si[N_];
  __shared__ int   t2[128];

  s[t]  = logits[b * N_ + t];
  si[t] = t;
  __syncthreads();

  for (int k = 2; k <= N_; k <<= 1) {
    for (int j = k >> 1; j > 0; j >>= 1) {
      int ixj = t ^ j;
      if (ixj > t) {
        float s1 = s[t], s2 = s[ixj];
        int   i1 = si[t], i2 = si[ixj];
        bool before = (s1 > s2) || (s1 == s2 && i1 < i2);
        bool doSwap = ((t & k) == 0) ? !before : before;
        if (doSwap) { s[t] = s2; s[ixj] = s1; si[t] = i2; si[ixj] = i1; }
      }
      __syncthreads();
    }
  }

  if (t < 128) t2[t] = (t < KEEP) ? si[t] : 0x7FFFFFFF;
  __syncthreads();
  for (int k = 2; k <= 128; k <<= 1) {
    for (int j = k >> 1; j > 0; j >>= 1) {
      if (t < 128) {
        int ixj = t ^ j;
        if (ixj > t) {
          int a = t2[t], c = t2[ixj];
          bool before = a < c;
          bool doSwap = ((t & k) == 0) ? !before : before;
          if (doSwap) { t2[t] = c; t2[ixj] = a; }
        }
      }
      __syncthreads();
    }
  }

  if (t < KEEP) {
    int v = t2[t];
    idx_ws[b * KEEP + t] = v;
    out[out_idx_base + b * KEEP + t] = (float)v;
  }
}

// ---------------------------------------------------------------------------
// Kernel 4: gather selected rows + register token.
// ---------------------------------------------------------------------------
__global__ __launch_bounds__(192) void gather_kernel(
    const float* __restrict__ A,        // dense_visual [B, N, DV]
    const float* __restrict__ reg_tok,  // [DV]
    const int* __restrict__ idx_ws,     // [B, KEEP]
    float* __restrict__ out) {          // [B, KEEP+1, DV]
  int blk = blockIdx.x;
  int b = blk / (KEEP + 1), r = blk % (KEEP + 1);
  int t = threadIdx.x;
  const float* src;
  if (r == KEEP) {
    src = reg_tok;
  } else {
    int idx = idx_ws[b * KEEP + r];
    src = A + ((size_t)b * N_ + idx) * DV;
  }
  float4 v = *(const float4*)&src[t * 4];
  *(float4*)&out[((size_t)b * (KEEP + 1) + r) * DV + t * 4] = v;
}

// ---------------------------------------------------------------------------
extern "C" void kernel_launch(void* const* d_in, const int* in_sizes, int n_in,
                              void* d_out, int out_size, void* d_ws, size_t ws_size,
                              hipStream_t stream) {
  (void)in_sizes; (void)n_in; (void)out_size; (void)ws_size;
  const float* dense_visual = (const float*)d_in[0];
  const float* text_emb     = (const float*)d_in[1];
  const float* W1           = (const float*)d_in[2];
  const float* b1           = (const float*)d_in[3];
  const float* W2           = (const float*)d_in[4];
  // d_in[5] = b2: monotonic shift, irrelevant to ranking
  const float* reg_tok      = (const float*)d_in[6];
  float* out = (float*)d_out;

  // ws layout (bytes):
  //   ctx_proj: 64*256*4      =  65536   @ 0
  //   logits  : 64*1024*4     = 262144   @ 65536
  //   idx     : 64*96*4       =  24576   @ 327680
  //   Wh      : 768*256*2     = 393216   @ 352256 (16B aligned)
  //   Wl      : 768*256*2     = 393216   @ 745472
  char* ws = (char*)d_ws;
  float*     ctx_proj = (float*)(ws + 0);
  float*     logits   = (float*)(ws + 65536);
  int*       idx_ws   = (int*)(ws + 327680);
  _Float16*  Wh       = (_Float16*)(ws + 352256);
  _Float16*  Wl       = (_Float16*)(ws + 745472);

  const int out_idx_base = B_ * (KEEP + 1) * DV;

  pack_w_kernel<<<DV, 256, 0, stream>>>(W1, Wh, Wl);
  ctx_proj_kernel<<<B_, 1024, 0, stream>>>(text_emb, W1, b1, ctx_proj);
  score_kernel<<<(B_ * N_) / 64, 256, 0, stream>>>(dense_visual, Wh, Wl, W2, ctx_proj, logits);
  topk_kernel<<<B_, 1024, 0, stream>>>(logits, idx_ws, out, out_idx_base);
  gather_kernel<<<B_ * (KEEP + 1), 192, 0, stream>>>(dense_visual, reg_tok, idx_ws, out);
}

// Round 5
// 361.827 us; speedup vs baseline: 2.4543x; 1.0466x over previous
//
#include <hip/hip_runtime.h>
#include <hip/hip_bf16.h>

// Problem constants (from reference)
#define B_   64
#define N_   1024
#define S_   64
#define DV   768
#define DT   768
#define HID  256
#define KEEP 96

#define KB2  64            // K per staged tile
#define NKS2 (DV / KB2)    // 12 K-steps
#define SCALE_A 32.0f      // keeps f16 split residuals in normal range
#define SCALE_W 32.0f
#define SCALE_LOGIT (SCALE_A * SCALE_W)

typedef _Float16 half8_t __attribute__((ext_vector_type(8)));  // 4 VGPRs
typedef float f32x4 __attribute__((ext_vector_type(4)));

// ---------------------------------------------------------------------------
// Kernel 0: split W1[0:768][:] (scaled x32) into f16 hi/lo, stored in MFMA
// B-fragment lane order: for 32-k-group g=d>>5: Wpack[(g*16 + c)*64 + lane][i]
// holds W[g*32 + (lane>>4)*8 + i][c*16 + (lane&15)].
// ---------------------------------------------------------------------------
__global__ __launch_bounds__(256) void pack_w_kernel(
    const float* __restrict__ W1, _Float16* __restrict__ Wh,
    _Float16* __restrict__ Wl) {
  int d = blockIdx.x;    // 0..767
  int h = threadIdx.x;   // 0..255
  float w = W1[d * HID + h] * SCALE_W;
  _Float16 hi = (_Float16)w;
  _Float16 lo = (_Float16)(w - (float)hi);
  int g = d >> 5, r = d & 31;
  int lane = ((r >> 3) << 4) | (h & 15);
  int i = r & 7, c = h >> 4;
  size_t off = ((size_t)((g * 16 + c) * 64 + lane)) * 8 + i;
  Wh[off] = hi;
  Wl[off] = lo;
}

// ---------------------------------------------------------------------------
// Kernel 1: ctx_proj[b][h] = 1024*(b1[h] + mean_s(text) . W1[768:1536][h])
// ---------------------------------------------------------------------------
__global__ __launch_bounds__(1024) void ctx_proj_kernel(
    const float* __restrict__ text,   // [B, S, DT]
    const float* __restrict__ W1,     // [DV+DT, HID]
    const float* __restrict__ b1,     // [HID]
    float* __restrict__ ctx_proj) {   // [B, HID]
  int b = blockIdx.x;
  int t = threadIdx.x;
  __shared__ float ctx[DT];
  __shared__ float red[4][HID];
  if (t < DT) {
    const float* p = text + (size_t)b * S_ * DT + t;
    float a0 = 0.f, a1 = 0.f, a2 = 0.f, a3 = 0.f;
    for (int s = 0; s < S_; s += 4) {
      a0 += p[(size_t)(s + 0) * DT];
      a1 += p[(size_t)(s + 1) * DT];
      a2 += p[(size_t)(s + 2) * DT];
      a3 += p[(size_t)(s + 3) * DT];
    }
    ctx[t] = ((a0 + a1) + (a2 + a3)) * (1.0f / S_);
  }
  __syncthreads();
  int p4 = t >> 8;        // 0..3
  int h  = t & 255;
  int db = p4 * 192;
  const float* wcol = W1 + (size_t)(DV + db) * HID + h;
  float s0 = 0.f, s1 = 0.f, s2 = 0.f, s3 = 0.f;
  #pragma unroll 4
  for (int d = 0; d < 192; d += 4) {
    s0 = fmaf(ctx[db + d + 0], wcol[(size_t)(d + 0) * HID], s0);
    s1 = fmaf(ctx[db + d + 1], wcol[(size_t)(d + 1) * HID], s1);
    s2 = fmaf(ctx[db + d + 2], wcol[(size_t)(d + 2) * HID], s2);
    s3 = fmaf(ctx[db + d + 3], wcol[(size_t)(d + 3) * HID], s3);
  }
  red[p4][h] = ((s0 + s1) + (s2 + s3));
  __syncthreads();
  if (t < HID)
    ctx_proj[b * HID + t] =
        SCALE_LOGIT * (b1[t] + ((red[0][t] + red[1][t]) + (red[2][t] + red[3][t])));
}

// ---------------------------------------------------------------------------
// Kernel 2: MFMA f16x3 scorer, counted-vmcnt software pipeline.
// Queue discipline (per wave, steady state):
//   top:   issue A[ks+1] (4 HBM loads)
//   ksub0: issue B[2ks+1] (8 L2 loads) ; wait B[2ks] = vmcnt(12) ; MFMA 48
//   ksub1: issue B[2ks+2] ; wait B[2ks+1] = vmcnt(8) (drains A too — consume
//          A right here: cvt + ds_write buf[nxt]) ; MFMA 48
//   raw s_barrier with lgkmcnt(0) only — B[2ks+2] stays in flight across it.
// ---------------------------------------------------------------------------
__device__ inline void cvt_split8(float4 a, float4 b, half8_t& hi, half8_t& lo) {
  float x[8] = {a.x, a.y, a.z, a.w, b.x, b.y, b.z, b.w};
  #pragma unroll
  for (int i = 0; i < 8; ++i) {
    float v = x[i] * SCALE_A;
    _Float16 h = (_Float16)v;
    hi[i] = h;
    lo[i] = (_Float16)(v - (float)h);
  }
}

__device__ inline void lds_barrier() {
  asm volatile("s_waitcnt lgkmcnt(0)" ::: "memory");
  __builtin_amdgcn_sched_barrier(0);
  __builtin_amdgcn_s_barrier();
  asm volatile("" ::: "memory");
}

__global__ __launch_bounds__(256, 2) void score_kernel(
    const float* __restrict__ A,          // dense_visual [B*N, DV]
    const _Float16* __restrict__ WhP,     // packed hi [(24*16)*64][8]
    const _Float16* __restrict__ WlP,     // packed lo
    const float* __restrict__ W2,         // [HID]
    const float* __restrict__ ctx_proj,   // [B, HID] (scaled)
    float* __restrict__ logits) {         // [B*N] (scaled)
  // A-tile layout (half8 units): [g*64 + row], g = k/8 (0..7), row<64
  __shared__ half8_t AhS[2][512];   // 16 KB
  __shared__ half8_t AlS[2][512];   // 16 KB
  __shared__ float red[64][4];

  const int t = threadIdx.x;
  const int lane = t & 63;
  const int w = t >> 6;
  const int r0 = blockIdx.x * 64;
  const int batch = r0 >> 10;

  // staging: thread t loads row (t>>2), 16 consecutive k at (t&3)*16
  const int arow = t >> 2;
  const int k0 = (t & 3) * 16;
  const float* aptr = A + (size_t)(r0 + arow) * DV + k0;
  const int dst1 = ((t & 3) * 2) * 64 + arow;   // half8-group index g=k0/8
  const int dst2 = dst1 + 64;

  const half8_t* WhV = (const half8_t*)WhP;
  const half8_t* WlV = (const half8_t*)WlP;

  f32x4 acc[4][4];
  #pragma unroll
  for (int rt = 0; rt < 4; ++rt)
    #pragma unroll
    for (int j = 0; j < 4; ++j) acc[rt][j] = (f32x4){0.f, 0.f, 0.f, 0.f};

  // B register pipeline: even 32-k-groups in bh0/bl0, odd in bh1/bl1
  half8_t bh0[4], bl0[4], bh1[4], bl1[4];

  // ---- prologue: stage A[0]; issue B[0] ----
  {
    float4 v0 = *(const float4*)(aptr + 0);
    float4 v1 = *(const float4*)(aptr + 4);
    float4 v2 = *(const float4*)(aptr + 8);
    float4 v3 = *(const float4*)(aptr + 12);
    half8_t h0, l0, h1, l1;
    cvt_split8(v0, v1, h0, l0);
    cvt_split8(v2, v3, h1, l1);
    AhS[0][dst1] = h0; AlS[0][dst1] = l0;
    AhS[0][dst2] = h1; AlS[0][dst2] = l1;
  }
  #pragma unroll
  for (int j = 0; j < 4; ++j) {
    int bi = (w * 4 + j) * 64 + lane;     // g = 0
    bh0[j] = WhV[bi];
    bl0[j] = WlV[bi];
  }
  lds_barrier();

  float4 av0, av1, av2, av3;
  #pragma unroll 2
  for (int ks = 0; ks < NKS2; ++ks) {
    const int cur = ks & 1;
    // top: issue next A tile (HBM; consumed at ksub1 after ~full iteration)
    if (ks + 1 < NKS2) {
      const float* ap = aptr + (ks + 1) * KB2;
      av0 = *(const float4*)(ap + 0);
      av1 = *(const float4*)(ap + 4);
      av2 = *(const float4*)(ap + 8);
      av3 = *(const float4*)(ap + 12);
    }

    // ---- ksub0: issue B[odd g], compute on B[even g] ----
    {
      const int g = 2 * ks + 1;           // always <= 23
      #pragma unroll
      for (int j = 0; j < 4; ++j) {
        int bi = (g * 16 + w * 4 + j) * 64 + lane;
        bh1[j] = WhV[bi];
        bl1[j] = WlV[bi];
      }
    }
    {
      half8_t ah[4], al[4];
      #pragma unroll
      for (int rt = 0; rt < 4; ++rt) {
        int ai = (lane >> 4) * 64 + rt * 16 + (lane & 15);  // ksub0
        ah[rt] = AhS[cur][ai];
        al[rt] = AlS[cur][ai];
      }
      #pragma unroll
      for (int rt = 0; rt < 4; ++rt)
        #pragma unroll
        for (int j = 0; j < 4; ++j) {
          acc[rt][j] = __builtin_amdgcn_mfma_f32_16x16x32_f16(ah[rt], bh0[j], acc[rt][j], 0, 0, 0);
          acc[rt][j] = __builtin_amdgcn_mfma_f32_16x16x32_f16(ah[rt], bl0[j], acc[rt][j], 0, 0, 0);
          acc[rt][j] = __builtin_amdgcn_mfma_f32_16x16x32_f16(al[rt], bh0[j], acc[rt][j], 0, 0, 0);
        }
    }

    // ---- ksub1: issue B[next even g], consume A, compute on B[odd g] ----
    if (ks + 1 < NKS2) {
      const int g = 2 * ks + 2;
      #pragma unroll
      for (int j = 0; j < 4; ++j) {
        int bi = (g * 16 + w * 4 + j) * 64 + lane;
        bh0[j] = WhV[bi];
        bl0[j] = WlV[bi];
      }
      // A is force-drained by the bh1 wait anyway — consume it here
      half8_t h0, l0, h1, l1;
      cvt_split8(av0, av1, h0, l0);
      cvt_split8(av2, av3, h1, l1);
      AhS[cur ^ 1][dst1] = h0; AlS[cur ^ 1][dst1] = l0;
      AhS[cur ^ 1][dst2] = h1; AlS[cur ^ 1][dst2] = l1;
    }
    {
      half8_t ah[4], al[4];
      #pragma unroll
      for (int rt = 0; rt < 4; ++rt) {
        int ai = (4 + (lane >> 4)) * 64 + rt * 16 + (lane & 15);  // ksub1
        ah[rt] = AhS[cur][ai];
        al[rt] = AlS[cur][ai];
      }
      #pragma unroll
      for (int rt = 0; rt < 4; ++rt)
        #pragma unroll
        for (int j = 0; j < 4; ++j) {
          acc[rt][j] = __builtin_amdgcn_mfma_f32_16x16x32_f16(ah[rt], bh1[j], acc[rt][j], 0, 0, 0);
          acc[rt][j] = __builtin_amdgcn_mfma_f32_16x16x32_f16(ah[rt], bl1[j], acc[rt][j], 0, 0, 0);
          acc[rt][j] = __builtin_amdgcn_mfma_f32_16x16x32_f16(al[rt], bh1[j], acc[rt][j], 0, 0, 0);
        }
    }
    // raw barrier: LDS visibility only; B[2ks+2] loads stay in flight
    lds_barrier();
  }

  // epilogue: +ctx, relu, dot W2 over this wave's 64 cols, reduce
  const int hbase = w * 64 + (lane & 15);
  const float* ctxp = ctx_proj + batch * HID;
  float psum[4][4];
  #pragma unroll
  for (int rt = 0; rt < 4; ++rt)
    #pragma unroll
    for (int r = 0; r < 4; ++r) psum[rt][r] = 0.f;
  #pragma unroll
  for (int j = 0; j < 4; ++j) {
    int hcol = hbase + j * 16;
    float cj = ctxp[hcol];
    float w2j = W2[hcol];
    #pragma unroll
    for (int rt = 0; rt < 4; ++rt)
      #pragma unroll
      for (int r = 0; r < 4; ++r)
        psum[rt][r] = fmaf(fmaxf(acc[rt][j][r] + cj, 0.f), w2j, psum[rt][r]);
  }
  #pragma unroll
  for (int m = 1; m < 16; m <<= 1)
    #pragma unroll
    for (int rt = 0; rt < 4; ++rt)
      #pragma unroll
      for (int r = 0; r < 4; ++r)
        psum[rt][r] += __shfl_xor(psum[rt][r], m, 64);
  if ((lane & 15) == 0) {
    int rowg = (lane >> 4) * 4;
    #pragma unroll
    for (int rt = 0; rt < 4; ++rt)
      #pragma unroll
      for (int r = 0; r < 4; ++r) red[rt * 16 + rowg + r][w] = psum[rt][r];
  }
  __syncthreads();
  if (t < 64) logits[r0 + t] = red[t][0] + red[t][1] + red[t][2] + red[t][3];
}

// ---------------------------------------------------------------------------
// Kernel 3: per-batch top-96 (ties -> lower index), then sort indices asc.
// ---------------------------------------------------------------------------
__global__ __launch_bounds__(1024) void topk_kernel(
    const float* __restrict__ logits,  // [B, N]
    int* __restrict__ idx_ws,          // [B, KEEP]
    float* __restrict__ out,           // d_out; idx tail at out_idx_base
    int out_idx_base) {
  int b = blockIdx.x;
  int t = threadIdx.x;
  __shared__ float s[N_];
  __shared__ int   si[N_];
  __shared__ int   t2[128];

  s[t]  = logits[b * N_ + t];
  si[t] = t;
  __syncthreads();

  for (int k = 2; k <= N_; k <<= 1) {
    for (int j = k >> 1; j > 0; j >>= 1) {
      int ixj = t ^ j;
      if (ixj > t) {
        float s1 = s[t], s2 = s[ixj];
        int   i1 = si[t], i2 = si[ixj];
        bool before = (s1 > s2) || (s1 == s2 && i1 < i2);
        bool doSwap = ((t & k) == 0) ? !before : before;
        if (doSwap) { s[t] = s2; s[ixj] = s1; si[t] = i2; si[ixj] = i1; }
      }
      __syncthreads();
    }
  }

  if (t < 128) t2[t] = (t < KEEP) ? si[t] : 0x7FFFFFFF;
  __syncthreads();
  for (int k = 2; k <= 128; k <<= 1) {
    for (int j = k >> 1; j > 0; j >>= 1) {
      if (t < 128) {
        int ixj = t ^ j;
        if (ixj > t) {
          int a = t2[t], c = t2[ixj];
          bool before = a < c;
          bool doSwap = ((t & k) == 0) ? !before : before;
          if (doSwap) { t2[t] = c; t2[ixj] = a; }
        }
      }
      __syncthreads();
    }
  }

  if (t < KEEP) {
    int v = t2[t];
    idx_ws[b * KEEP + t] = v;
    out[out_idx_base + b * KEEP + t] = (float)v;
  }
}

// ---------------------------------------------------------------------------
// Kernel 4: gather selected rows + register token.
// ---------------------------------------------------------------------------
__global__ __launch_bounds__(192) void gather_kernel(
    const float* __restrict__ A,        // dense_visual [B, N, DV]
    const float* __restrict__ reg_tok,  // [DV]
    const int* __restrict__ idx_ws,     // [B, KEEP]
    float* __restrict__ out) {          // [B, KEEP+1, DV]
  int blk = blockIdx.x;
  int b = blk / (KEEP + 1), r = blk % (KEEP + 1);
  int t = threadIdx.x;
  const float* src;
  if (r == KEEP) {
    src = reg_tok;
  } else {
    int idx = idx_ws[b * KEEP + r];
    src = A + ((size_t)b * N_ + idx) * DV;
  }
  float4 v = *(const float4*)&src[t * 4];
  *(float4*)&out[((size_t)b * (KEEP + 1) + r) * DV + t * 4] = v;
}

// ---------------------------------------------------------------------------
extern "C" void kernel_launch(void* const* d_in, const int* in_sizes, int n_in,
                              void* d_out, int out_size, void* d_ws, size_t ws_size,
                              hipStream_t stream) {
  (void)in_sizes; (void)n_in; (void)out_size; (void)ws_size;
  const float* dense_visual = (const float*)d_in[0];
  const float* text_emb     = (const float*)d_in[1];
  const float* W1           = (const float*)d_in[2];
  const float* b1           = (const float*)d_in[3];
  const float* W2           = (const float*)d_in[4];
  // d_in[5] = b2: monotonic shift, irrelevant to ranking
  const float* reg_tok      = (const float*)d_in[6];
  float* out = (float*)d_out;

  // ws layout (bytes):
  //   ctx_proj: 64*256*4      =  65536   @ 0
  //   logits  : 64*1024*4     = 262144   @ 65536
  //   idx     : 64*96*4       =  24576   @ 327680
  //   Wh      : 768*256*2     = 393216   @ 352256 (16B aligned)
  //   Wl      : 768*256*2     = 393216   @ 745472
  char* ws = (char*)d_ws;
  float*     ctx_proj = (float*)(ws + 0);
  float*     logits   = (float*)(ws + 65536);
  int*       idx_ws   = (int*)(ws + 327680);
  _Float16*  Wh       = (_Float16*)(ws + 352256);
  _Float16*  Wl       = (_Float16*)(ws + 745472);

  const int out_idx_base = B_ * (KEEP + 1) * DV;

  pack_w_kernel<<<DV, 256, 0, stream>>>(W1, Wh, Wl);
  ctx_proj_kernel<<<B_, 1024, 0, stream>>>(text_emb, W1, b1, ctx_proj);
  score_kernel<<<(B_ * N_) / 64, 256, 0, stream>>>(dense_visual, Wh, Wl, W2, ctx_proj, logits);
  topk_kernel<<<B_, 1024, 0, stream>>>(logits, idx_ws, out, out_idx_base);
  gather_kernel<<<B_ * (KEEP + 1), 192, 0, stream>>>(dense_visual, reg_tok, idx_ws, out);
}